// Round 2
// baseline (67.178 us; speedup 1.0000x reference)
//
#include <hip/hip_runtime.h>
#include <math.h>

// Problem constants (from reference)
#define NN      131072          // ROWS*COLS*P = 64*64*32
#define Q       10
#define T1      8
#define GRID    2048
#define BLOCK   256

// d_out layout (float32, concatenated in return order):
//   [0, 10)                         prediction
//   [10, 10 + N*Q*T1)               voter_in[0]   (10,485,760)
//   [10 + N*Q*T1, ... + 2*N*Q*T1)   votes         (20,971,520)
#define VIN0_OFF   10u
#define VIN0_SZ    (NN * Q * T1)            // 10485760
#define VOTES_OFF  (VIN0_OFF + VIN0_SZ)     // 10485770 (2 mod 4 -> 8B aligned)
#define VOTES_SZ   (2u * NN * Q * T1)       // 20971520
#define E_F2       (VOTES_SZ / 2u)          // 10,485,760 float2s of votes

// One thread per float2 of `votes`. j -> (row r = j>>2, slot = j&3).
// Weight float2 for this j is exactly weights2[j] (same (s,i,q,t) linearization)
// -> perfectly coalesced 8B read stream covering all 84 MB.
__global__ __launch_bounds__(BLOCK) void dtnn_main(
    const float* __restrict__ spikes,   // (N,)
    const float* __restrict__ weights,  // (2, N, Q, T1)
    float* __restrict__ out,
    unsigned int* __restrict__ tallies) // (Q, GRID) per-block partials in d_ws
{
    __shared__ unsigned int lt[Q];
    if (threadIdx.x < Q) lt[threadIdx.x] = 0u;
    __syncthreads();

    const float2* __restrict__ w2p    = (const float2*)weights;
    float2* __restrict__       votes2 = (float2*)(out + VOTES_OFF);
    float2* __restrict__       vin2   = (float2*)(out + VIN0_OFF);

    const unsigned int stride = GRID * BLOCK;
    for (unsigned int j = blockIdx.x * BLOCK + threadIdx.x; j < E_F2; j += stride) {
        const unsigned int r    = j >> 2;          // (s,i,q) row
        const unsigned int slot = j & 3u;          // which float2 of the 8-bin row
        const unsigned int q    = r % Q;
        const unsigned int ri   = r / Q;           // s*N + i
        const unsigned int i    = ri & (NN - 1u);

        float v = spikes[i];
        if (v >= 7.0f && !isinf(v)) v = 7.0f;      // clamp finite >= tau_eff; Inf passes through
        const float t0 = (float)(slot * 2u);
        const float t1 = t0 + 1.0f;
        const bool  h0 = (v == t0);                // one-hot via exact float compare
        const bool  h1 = (v == t1);                // (Inf / out-of-range -> all zero)

        const float2 w  = w2p[j];                  // coalesced
        const float  vx = (h0 && w.x >= 3.5f) ? 1.0f : 0.0f;
        const float  vy = (h1 && w.y >= 3.5f) ? 1.0f : 0.0f;
        votes2[j] = make_float2(vx, vy);

        if (r < NN * Q) {                          // s == 0: emit voter_in[0]
            vin2[j] = make_float2(h0 ? 1.0f : 0.0f, h1 ? 1.0f : 0.0f);
        }

        // at most one of vx/vy is nonzero (one-hot in t)
        if ((vx != 0.0f) | (vy != 0.0f)) atomicAdd(&lt[q], 1u);
    }

    __syncthreads();
    if (threadIdx.x < Q)
        tallies[threadIdx.x * GRID + blockIdx.x] = lt[threadIdx.x];  // store, no atomics
}

__global__ __launch_bounds__(BLOCK) void dtnn_pred(
    const unsigned int* __restrict__ tallies,  // (Q, GRID)
    float* __restrict__ out)
{
    __shared__ unsigned int lt[Q];
    if (threadIdx.x < Q) lt[threadIdx.x] = 0u;
    __syncthreads();

    unsigned int local[Q];
    #pragma unroll
    for (int q = 0; q < Q; ++q) local[q] = 0u;

    for (unsigned int b = threadIdx.x; b < GRID; b += BLOCK) {
        #pragma unroll
        for (int q = 0; q < Q; ++q) local[q] += tallies[q * GRID + b];  // coalesced per q
    }
    #pragma unroll
    for (int q = 0; q < Q; ++q) atomicAdd(&lt[q], local[q]);
    __syncthreads();

    if (threadIdx.x == 0) {
        unsigned int best = lt[0]; int bi = 0;
        #pragma unroll
        for (int q = 1; q < Q; ++q)
            if (lt[q] > best) { best = lt[q]; bi = q; }   // first-index tie-break (JAX argmax)
        #pragma unroll
        for (int q = 0; q < Q; ++q) out[q] = (q == bi) ? 1.0f : 0.0f;
    }
}

extern "C" void kernel_launch(void* const* d_in, const int* in_sizes, int n_in,
                              void* d_out, int out_size, void* d_ws, size_t ws_size,
                              hipStream_t stream) {
    const float* spikes  = (const float*)d_in[0];   // (64,64,32) float32
    const float* weights = (const float*)d_in[1];   // (2, N, Q, T1) float32
    float* out = (float*)d_out;
    unsigned int* tallies = (unsigned int*)d_ws;    // Q * GRID uints = 80 KB

    dtnn_main<<<GRID, BLOCK, 0, stream>>>(spikes, weights, out, tallies);
    dtnn_pred<<<1, BLOCK, 0, stream>>>(tallies, out);
}

// Round 3
// 42.254 us; speedup vs baseline: 1.5899x; 1.5899x over previous
//
#include <hip/hip_runtime.h>
#include <math.h>

// Problem constants (from reference)
#define NN      131072          // ROWS*COLS*P = 64*64*32
#define Q       10
#define T1      8
#define GRID    2048
#define BLOCK   256

// d_out layout (float32, concatenated in return order):
//   [0, 10)                         prediction
//   [10, 10 + N*Q*T1)               voter_in[0]   (10,485,760)
//   [10 + N*Q*T1, ... + 2*N*Q*T1)   votes         (20,971,520)
#define VIN0_OFF   10u
#define VIN0_SZ    (NN * Q * T1)            // 10485760
#define VOTES_OFF  (VIN0_OFF + VIN0_SZ)     // 10485770 (8B-aligned)
#define VOTES_SZ   (2u * NN * Q * T1)       // 20971520
#define E_F2       (VOTES_SZ / 2u)          // 10,485,760 float2s of votes

// One thread per float2 of `votes`; j -> row r = j>>2, slot = j&3.
// Tally via wave ballots (no LDS atomics), per-block partials in d_ws.
__global__ __launch_bounds__(BLOCK) void dtnn_main(
    const float* __restrict__ spikes,   // (N,)
    const float* __restrict__ weights,  // (2, N, Q, T1)
    float* __restrict__ out,
    unsigned int* __restrict__ tallies) // (Q, GRID)
{
    const unsigned int lane = threadIdx.x & 63u;
    const unsigned int wid  = threadIdx.x >> 6;   // 4 waves/block

    float2* __restrict__ votes2 = (float2*)(out + VOTES_OFF);
    float2* __restrict__ vin2   = (float2*)(out + VIN0_OFF);

    unsigned int acc = 0u;   // lane k (<10) accumulates tally for class k

    const unsigned int stride = GRID * BLOCK;
    for (unsigned int j = blockIdx.x * BLOCK + threadIdx.x; j < E_F2; j += stride) {
        const unsigned int r    = j >> 2;          // (s,i,q) row
        const unsigned int slot = j & 3u;          // which float2 of the 8-bin row
        const unsigned int q    = r % Q;
        const unsigned int ri   = r / Q;           // s*N + i
        const unsigned int i    = ri & (NN - 1u);

        float v = spikes[i];
        if (v >= 7.0f && !isinf(v)) v = 7.0f;      // clamp finite >= tau_eff
        const int  tv    = (int)v;
        const bool valid = (v >= 0.0f) && (v < 8.0f) && ((float)tv == v);
        const bool owns  = valid && ((unsigned)(tv >> 1) == slot);

        float2 o   = make_float2(0.0f, 0.0f);
        bool   inc = false;
        if (owns) {                                 // exec-masked scalar load (R1-proven)
            const float w    = weights[r * 8u + (unsigned)tv];
            const float vote = (w >= 3.5f) ? 1.0f : 0.0f;
            if (tv & 1) o.y = vote; else o.x = vote;
            inc = (vote != 0.0f);
        }
        votes2[j] = o;

        if (r < NN * Q) {                           // s == 0: emit voter_in[0]
            float2 h = make_float2(0.0f, 0.0f);
            if (owns) { if (tv & 1) h.y = 1.0f; else h.x = 1.0f; }
            vin2[j] = h;
        }

        // Wave-level tally: 10 ballots, zero LDS traffic.
        #pragma unroll
        for (int k = 0; k < Q; ++k) {
            const unsigned long long m = __ballot(inc && (q == (unsigned)k));
            if (lane == (unsigned)k) acc += (unsigned)__popcll(m);
        }
    }

    // Combine 4 waves' lane-resident tallies via plain LDS stores.
    __shared__ unsigned int lt[4 * Q];
    if (lane < Q) lt[wid * Q + lane] = acc;
    __syncthreads();
    if (threadIdx.x < Q) {
        tallies[threadIdx.x * GRID + blockIdx.x] =
            lt[threadIdx.x] + lt[Q + threadIdx.x] + lt[2 * Q + threadIdx.x] + lt[3 * Q + threadIdx.x];
    }
}

// One wave per class: coalesced partial loads + shuffle reduction.
__global__ __launch_bounds__(64 * Q) void dtnn_pred(
    const unsigned int* __restrict__ tallies,  // (Q, GRID)
    float* __restrict__ out)
{
    const unsigned int lane = threadIdx.x & 63u;
    const unsigned int q    = threadIdx.x >> 6;    // 0..9

    unsigned int s = 0;
    #pragma unroll
    for (int it = 0; it < GRID / 64; ++it)
        s += tallies[q * GRID + it * 64 + lane];
    #pragma unroll
    for (int off = 32; off >= 1; off >>= 1)
        s += __shfl_down(s, off, 64);

    __shared__ unsigned int sums[Q];
    if (lane == 0) sums[q] = s;
    __syncthreads();

    if (threadIdx.x == 0) {
        unsigned int best = sums[0]; int bi = 0;
        #pragma unroll
        for (int k = 1; k < Q; ++k)
            if (sums[k] > best) { best = sums[k]; bi = k; }   // first-index tie-break
        #pragma unroll
        for (int k = 0; k < Q; ++k) out[k] = (k == bi) ? 1.0f : 0.0f;
    }
}

extern "C" void kernel_launch(void* const* d_in, const int* in_sizes, int n_in,
                              void* d_out, int out_size, void* d_ws, size_t ws_size,
                              hipStream_t stream) {
    const float* spikes  = (const float*)d_in[0];   // (64,64,32) float32
    const float* weights = (const float*)d_in[1];   // (2, N, Q, T1) float32
    float* out = (float*)d_out;
    unsigned int* tallies = (unsigned int*)d_ws;    // Q * GRID uints = 80 KB

    dtnn_main<<<GRID, BLOCK, 0, stream>>>(spikes, weights, out, tallies);
    dtnn_pred<<<1, 64 * Q, 0, stream>>>(tallies, out);
}